// Round 5
// baseline (484.796 us; speedup 1.0000x reference)
//
#include <hip/hip_runtime.h>
#include <stdint.h>
#include <stddef.h>

#define NE 600000
#define NN 50000
#define CI 128
#define CH 256
#define EPSI 1e-5f

typedef __attribute__((ext_vector_type(8))) short bf8;
typedef __attribute__((ext_vector_type(4))) float f4;
typedef __attribute__((ext_vector_type(4))) unsigned int u4;

union FragU { bf8 h; uint32_t w[4]; };

__device__ __forceinline__ unsigned short f2bf(float f) {
  union { float f; uint32_t u; } v; v.f = f;
  uint32_t u = v.u;
  u += 0x7FFFu + ((u >> 16) & 1u);   // RNE
  return (unsigned short)(u >> 16);
}

__device__ __forceinline__ uint32_t cvtpk(float lo, float hi) {
  uint32_t r;
  asm("v_cvt_pk_bf16_f32 %0, %1, %2" : "=v"(r) : "v"(lo), "v"(hi));
  return r;
}

__device__ __forceinline__ float asf(uint32_t x) {
  union { uint32_t u; float f; } v; v.u = x; return v.f;
}

// Weight pack (verified rounds 3/4):
//  P1 (layer1, per net, 64KB): tau-permuted so D-regs of chunk c land as
//    lane kg's hids {32c+8kg+0..7}.
//  P2 (layer2, per net, 64KB): u16 P2[mt][c][l][j] = W2[32c+(l>>4)*8+j][16mt+(l&15)]
// ws u16 layout: [0)P1a [32768)P1b [65536)P2a [98304)P2b [131072) Ua bf16 [NN][256]
__global__ void pack_weights(const float* __restrict__ W1a, const float* __restrict__ W1b,
                             const float* __restrict__ W2a, const float* __restrict__ W2b,
                             unsigned short* __restrict__ ws) {
  int i = blockIdx.x * 256 + threadIdx.x;
  if (i >= 4 * 32768) return;
  int m = i >> 15;
  int r = i & 32767;
  int j = r & 7;
  int l = (r >> 3) & 63;
  int kg = l >> 4, q = l & 15;
  float val;
  if (m < 2) {
    int t = (r >> 9) & 3;
    int tau = (r >> 11) & 1;
    int c = (r >> 12) & 7;
    int cin = 32 * t + kg * 8 + j;
    int hid = 32 * c + 8 * (q >> 2) + 4 * tau + (q & 3);
    const float* W1 = (m == 0) ? W1a : W1b;
    val = W1[cin * CH + hid];
  } else {
    int c = (r >> 9) & 7;
    int mt = (r >> 12) & 7;
    int hid = 32 * c + kg * 8 + j;
    int cout = 16 * mt + q;
    const float* W2 = (m == 2) ? W2a : W2b;
    val = W2[hid * CI + cout];
  }
  ws[(size_t)m * 32768 + r] = f2bf(val);
}

// Ua[n][hid] = bf16( node[n] @ W1a + 0.5*b1a )  (no relu; summed per edge later)
__global__ __launch_bounds__(256)
void node_pre(const float* __restrict__ node, const float* __restrict__ b1a,
              const unsigned short* __restrict__ wp, unsigned short* __restrict__ Ua) {
  const int tid = threadIdx.x;
  const int lane = tid & 63;
  const int wv = tid >> 6;
  const int kg = lane >> 4, ar = lane & 15;
  const int n0 = blockIdx.x * 64 + wv * 16 + ar;
  const bool okn = (n0 < NN);
  const int n = okn ? n0 : (NN - 1);
  const float* pn = node + (size_t)n * CI;

  FragU xn[4];
#pragma unroll
  for (int t = 0; t < 4; ++t) {
    const int c0 = t * 32 + kg * 8;
    f4 v0 = *(const f4*)(pn + c0);
    f4 v1 = *(const f4*)(pn + c0 + 4);
    xn[t].w[0] = cvtpk(v0[0], v0[1]); xn[t].w[1] = cvtpk(v0[2], v0[3]);
    xn[t].w[2] = cvtpk(v1[0], v1[1]); xn[t].w[3] = cvtpk(v1[2], v1[3]);
  }
  const int lofs = lane * 8;
#pragma unroll 1
  for (int c = 0; c < 8; ++c) {
    f4 t0 = *(const f4*)(b1a + c * 32 + kg * 8) * 0.5f;
    f4 t1 = *(const f4*)(b1a + c * 32 + kg * 8 + 4) * 0.5f;
    const unsigned short* p1 = wp + c * 4096;
#pragma unroll
    for (int t = 0; t < 4; ++t) {
      bf8 a0 = *(const bf8*)(p1 + t * 512 + lofs);
      bf8 a1 = *(const bf8*)(p1 + 2048 + t * 512 + lofs);
      t0 = __builtin_amdgcn_mfma_f32_16x16x32_bf16(a0, xn[t].h, t0, 0, 0, 0);
      t1 = __builtin_amdgcn_mfma_f32_16x16x32_bf16(a1, xn[t].h, t1, 0, 0, 0);
    }
    u4 q;
    q[0] = cvtpk(t0[0], t0[1]); q[1] = cvtpk(t0[2], t0[3]);
    q[2] = cvtpk(t1[0], t1[1]); q[3] = cvtpk(t1[2], t1[3]);
    if (okn) *(u4*)(Ua + (size_t)n * CH + c * 32 + kg * 8) = q;
  }
}

// Fused edge kernel: 512 threads = 8 waves, 32 edges/wave (2 groups of 16).
// LDS (64 KB): P2a copy only -> 2 blocks/CU for phase overlap.
__global__ __launch_bounds__(512, 4)
void edge_fused(const unsigned short* __restrict__ Ua,
                const float* __restrict__ ef,
                const int* __restrict__ eidx,
                const float* __restrict__ b1b,
                const float* __restrict__ b2a, const float* __restrict__ b2b,
                const unsigned short* __restrict__ wp,
                float* __restrict__ out) {
  __shared__ __align__(16) unsigned short lw[32768];   // P2a, 64 KB
  const int tid = threadIdx.x;
  const int lane = tid & 63;
  const int wv = tid >> 6;          // 0..7
  const int kg = lane >> 4, ar = lane & 15;
  const int lofs = lane * 8;

  // ---- stage P2a into LDS (u4 copies; barrier below)
  {
    const u4* s2 = (const u4*)(wp + 65536);
    u4* l = (u4*)lw;
#pragma unroll
    for (int i = 0; i < 8; ++i) {
      int o = i * 512 + tid;
      l[o] = s2[o];
    }
  }

  const int be = blockIdx.x * 256 + wv * 32;
  const int e0 = be + ar, e1 = be + 16 + ar;
  const int ec0 = (e0 < NE) ? e0 : (NE - 1);
  const int ec1 = (e1 < NE) ? e1 : (NE - 1);

  const unsigned short* pUs0 = Ua + (size_t)eidx[ec0] * CH;
  const unsigned short* pUd0 = Ua + (size_t)eidx[NE + ec0] * CH;
  const unsigned short* pUs1 = Ua + (size_t)eidx[ec1] * CH;
  const unsigned short* pUd1 = Ua + (size_t)eidx[NE + ec1] * CH;

  // ---- h^T accumulators (lane: edge ar, couts 16mt+4kg+i), b2a+b2b folded in
  f4 hacc[2][8];
#pragma unroll
  for (int mt = 0; mt < 8; ++mt) {
    f4 u = *(const f4*)(b2a + mt * 16 + kg * 4);
    f4 v = *(const f4*)(b2b + mt * 16 + kg * 4);
    hacc[0][mt] = u + v;
    hacc[1][mt] = u + v;
  }

  __syncthreads();   // P2a staged

  // ---- phase B: layer-2a. 16 fully-unrolled (u,g) steps; gathers pipelined
  //      by the compiler under the reg cap; W2a A-frags from LDS.
#pragma unroll
  for (int s = 0; s < 16; ++s) {
    const int u = s >> 1, g = s & 1;
    const unsigned short* ps = g ? pUs1 : pUs0;
    const unsigned short* pd = g ? pUd1 : pUd0;
    const int ko = u * 32 + kg * 8;
    u4 av = *(const u4*)(ps + ko);
    u4 dv = *(const u4*)(pd + ko);
    FragU tb;
#pragma unroll
    for (int i = 0; i < 4; ++i) {
      float lo = asf(av[i] << 16) + asf(dv[i] << 16);
      float hi = asf(av[i] & 0xFFFF0000u) + asf(dv[i] & 0xFFFF0000u);
      tb.w[i] = cvtpk(fmaxf(lo, 0.f), fmaxf(hi, 0.f));
    }
#pragma unroll
    for (int mt = 0; mt < 8; ++mt) {
      bf8 a2 = *(const bf8*)(lw + (mt * 8 + u) * 512 + lofs);
      hacc[g][mt] = __builtin_amdgcn_mfma_f32_16x16x32_bf16(a2, tb.h, hacc[g][mt], 0, 0, 0);
    }
  }

  // ---- phase A: net-b, group-sequential; W1b + W2b frags from global (hot L2)
#pragma unroll
  for (int g = 0; g < 2; ++g) {
    const int ecg = g ? ec1 : ec0;
    const float* pe = ef + (size_t)ecg * CI;
    FragU xe[4];
#pragma unroll
    for (int t = 0; t < 4; ++t) {
      const int c0 = t * 32 + kg * 8;
      f4 v0 = *(const f4*)(pe + c0);
      f4 v1 = *(const f4*)(pe + c0 + 4);
      xe[t].w[0] = cvtpk(v0[0], v0[1]); xe[t].w[1] = cvtpk(v0[2], v0[3]);
      xe[t].w[2] = cvtpk(v1[0], v1[1]); xe[t].w[3] = cvtpk(v1[2], v1[3]);
    }
    const unsigned short* P1b = wp + 32768;
    const unsigned short* P2b = wp + 98304;
#pragma unroll 1
    for (int c = 0; c < 8; ++c) {
      f4 t0 = *(const f4*)(b1b + c * 32 + kg * 8);
      f4 t1 = *(const f4*)(b1b + c * 32 + kg * 8 + 4);
#pragma unroll
      for (int t = 0; t < 4; ++t) {
        bf8 a0 = *(const bf8*)(P1b + c * 4096 + t * 512 + lofs);
        bf8 a1 = *(const bf8*)(P1b + c * 4096 + 2048 + t * 512 + lofs);
        t0 = __builtin_amdgcn_mfma_f32_16x16x32_bf16(a0, xe[t].h, t0, 0, 0, 0);
        t1 = __builtin_amdgcn_mfma_f32_16x16x32_bf16(a1, xe[t].h, t1, 0, 0, 0);
      }
      FragU bf_;
      bf_.w[0] = cvtpk(fmaxf(t0[0], 0.f), fmaxf(t0[1], 0.f));
      bf_.w[1] = cvtpk(fmaxf(t0[2], 0.f), fmaxf(t0[3], 0.f));
      bf_.w[2] = cvtpk(fmaxf(t1[0], 0.f), fmaxf(t1[1], 0.f));
      bf_.w[3] = cvtpk(fmaxf(t1[2], 0.f), fmaxf(t1[3], 0.f));
#pragma unroll
      for (int mt = 0; mt < 8; ++mt) {
        bf8 a2 = *(const bf8*)(P2b + (mt * 8 + c) * 512 + lofs);
        hacc[g][mt] = __builtin_amdgcn_mfma_f32_16x16x32_bf16(a2, bf_.h, hacc[g][mt], 0, 0, 0);
      }
    }
  }

  // ---- phase C: InstanceNorm + relu + residual + store, per group
#pragma unroll
  for (int g = 0; g < 2; ++g) {
    float sum = 0.f, sq = 0.f;
#pragma unroll
    for (int mt = 0; mt < 8; ++mt)
#pragma unroll
      for (int i = 0; i < 4; ++i) { float v = hacc[g][mt][i]; sum += v; sq += v * v; }
    sum += __shfl_xor(sum, 16); sum += __shfl_xor(sum, 32);
    sq  += __shfl_xor(sq, 16);  sq  += __shfl_xor(sq, 32);
    const float mu = sum * (1.0f / 128.0f);
    const float var = sq * (1.0f / 128.0f) - mu * mu;
    const float rs = rsqrtf(var + EPSI);
    const int e = g ? e1 : e0;
    if (e < NE) {
      float* po = out + (size_t)e * CI;
      const float* pr = ef + (size_t)e * CI;
#pragma unroll
      for (int mt = 0; mt < 8; ++mt) {
        f4 r = *(const f4*)(pr + mt * 16 + kg * 4);
        f4 o;
#pragma unroll
        for (int i = 0; i < 4; ++i) {
          float n = (hacc[g][mt][i] - mu) * rs;
          o[i] = r[i] + fmaxf(n, 0.f);
        }
        *(f4*)(po + mt * 16 + kg * 4) = o;
      }
    }
  }
}

extern "C" void kernel_launch(void* const* d_in, const int* in_sizes, int n_in,
                              void* d_out, int out_size, void* d_ws, size_t ws_size,
                              hipStream_t stream) {
  const float* node = (const float*)d_in[0];
  const float* ef   = (const float*)d_in[1];
  const int* eidx   = (const int*)d_in[2];
  const float* W1a = (const float*)d_in[3];
  const float* b1a = (const float*)d_in[4];
  const float* W2a = (const float*)d_in[5];
  const float* b2a = (const float*)d_in[6];
  const float* W1b = (const float*)d_in[7];
  const float* b1b = (const float*)d_in[8];
  const float* W2b = (const float*)d_in[9];
  const float* b2b = (const float*)d_in[10];
  unsigned short* wp = (unsigned short*)d_ws;            // 256 KB packed weights
  unsigned short* Ua = wp + 131072;                       // 25.6 MB bf16 Ua
  float* outp = (float*)d_out;

  pack_weights<<<512, 256, 0, stream>>>(W1a, W1b, W2a, W2b, wp);
  node_pre<<<(NN + 63) / 64, 256, 0, stream>>>(node, b1a, wp, Ua);
  edge_fused<<<(NE + 255) / 256, 512, 0, stream>>>(
      Ua, ef, eidx, b1b, b2a, b2b, wp, outp);
}

// Round 6
// 444.116 us; speedup vs baseline: 1.0916x; 1.0916x over previous
//
#include <hip/hip_runtime.h>
#include <stdint.h>
#include <stddef.h>

#define NE 600000
#define NN 50000
#define CI 128
#define CH 256
#define EPSI 1e-5f

typedef __attribute__((ext_vector_type(8))) short bf8;
typedef __attribute__((ext_vector_type(4))) float f4;
typedef __attribute__((ext_vector_type(4))) unsigned int u4;

union FragU { bf8 h; uint32_t w[4]; };

__device__ __forceinline__ unsigned short f2bf(float f) {
  union { float f; uint32_t u; } v; v.f = f;
  uint32_t u = v.u;
  u += 0x7FFFu + ((u >> 16) & 1u);   // RNE
  return (unsigned short)(u >> 16);
}

__device__ __forceinline__ uint32_t cvtpk(float lo, float hi) {
  uint32_t r;
  asm("v_cvt_pk_bf16_f32 %0, %1, %2" : "=v"(r) : "v"(lo), "v"(hi));
  return r;
}

__device__ __forceinline__ float asf(uint32_t x) {
  union { uint32_t u; float f; } v; v.u = x; return v.f;
}

// Weight pack (verified rounds 3/4/5):
//  P1 (layer1, per net, 64KB): tau-permuted so D-regs of chunk c land as
//    lane kg's hids {32c+8kg+0..7}.
//  P2 (layer2, per net, 64KB): u16 P2[mt][c][l][j] = W2[32c+(l>>4)*8+j][16mt+(l&15)]
// ws u16 layout: [0)P1a [32768)P1b [65536)P2a [98304)P2b [131072) Ua bf16 [NN][256]
__global__ void pack_weights(const float* __restrict__ W1a, const float* __restrict__ W1b,
                             const float* __restrict__ W2a, const float* __restrict__ W2b,
                             unsigned short* __restrict__ ws) {
  int i = blockIdx.x * 256 + threadIdx.x;
  if (i >= 4 * 32768) return;
  int m = i >> 15;
  int r = i & 32767;
  int j = r & 7;
  int l = (r >> 3) & 63;
  int kg = l >> 4, q = l & 15;
  float val;
  if (m < 2) {
    int t = (r >> 9) & 3;
    int tau = (r >> 11) & 1;
    int c = (r >> 12) & 7;
    int cin = 32 * t + kg * 8 + j;
    int hid = 32 * c + 8 * (q >> 2) + 4 * tau + (q & 3);
    const float* W1 = (m == 0) ? W1a : W1b;
    val = W1[cin * CH + hid];
  } else {
    int c = (r >> 9) & 7;
    int mt = (r >> 12) & 7;
    int hid = 32 * c + kg * 8 + j;
    int cout = 16 * mt + q;
    const float* W2 = (m == 2) ? W2a : W2b;
    val = W2[hid * CI + cout];
  }
  ws[(size_t)m * 32768 + r] = f2bf(val);
}

// Ua[n][hid] = bf16( node[n] @ W1a + 0.5*b1a )  (no relu; summed per edge later)
__global__ __launch_bounds__(256)
void node_pre(const float* __restrict__ node, const float* __restrict__ b1a,
              const unsigned short* __restrict__ wp, unsigned short* __restrict__ Ua) {
  const int tid = threadIdx.x;
  const int lane = tid & 63;
  const int wv = tid >> 6;
  const int kg = lane >> 4, ar = lane & 15;
  const int n0 = blockIdx.x * 64 + wv * 16 + ar;
  const bool okn = (n0 < NN);
  const int n = okn ? n0 : (NN - 1);
  const float* pn = node + (size_t)n * CI;

  FragU xn[4];
#pragma unroll
  for (int t = 0; t < 4; ++t) {
    const int c0 = t * 32 + kg * 8;
    f4 v0 = *(const f4*)(pn + c0);
    f4 v1 = *(const f4*)(pn + c0 + 4);
    xn[t].w[0] = cvtpk(v0[0], v0[1]); xn[t].w[1] = cvtpk(v0[2], v0[3]);
    xn[t].w[2] = cvtpk(v1[0], v1[1]); xn[t].w[3] = cvtpk(v1[2], v1[3]);
  }
  const int lofs = lane * 8;
#pragma unroll 1
  for (int c = 0; c < 8; ++c) {
    f4 t0 = *(const f4*)(b1a + c * 32 + kg * 8) * 0.5f;
    f4 t1 = *(const f4*)(b1a + c * 32 + kg * 8 + 4) * 0.5f;
    const unsigned short* p1 = wp + c * 4096;
#pragma unroll
    for (int t = 0; t < 4; ++t) {
      bf8 a0 = *(const bf8*)(p1 + t * 512 + lofs);
      bf8 a1 = *(const bf8*)(p1 + 2048 + t * 512 + lofs);
      t0 = __builtin_amdgcn_mfma_f32_16x16x32_bf16(a0, xn[t].h, t0, 0, 0, 0);
      t1 = __builtin_amdgcn_mfma_f32_16x16x32_bf16(a1, xn[t].h, t1, 0, 0, 0);
    }
    u4 q;
    q[0] = cvtpk(t0[0], t0[1]); q[1] = cvtpk(t0[2], t0[3]);
    q[2] = cvtpk(t1[0], t1[1]); q[3] = cvtpk(t1[2], t1[3]);
    if (okn) *(u4*)(Ua + (size_t)n * CH + c * 32 + kg * 8) = q;
  }
}

// Fused edge kernel: 512 threads = 8 waves, 32 edges/wave (2 groups of 16).
// LDS (64 KB) = P1b copy -> 2 blocks/CU. Order: stage-issue, phase B (gathers,
// no LDS), barrier, phase A (LDS P1b + L2 P2b), epilogue.
__global__ __launch_bounds__(512, 4)
void edge_fused(const unsigned short* __restrict__ Ua,
                const float* __restrict__ ef,
                const int* __restrict__ eidx,
                const float* __restrict__ b1b,
                const float* __restrict__ b2a, const float* __restrict__ b2b,
                const unsigned short* __restrict__ wp,
                float* __restrict__ out) {
  __shared__ __align__(16) unsigned short lw[32768];   // P1b, 64 KB
  const int tid = threadIdx.x;
  const int lane = tid & 63;
  const int wv = tid >> 6;          // 0..7
  const int kg = lane >> 4, ar = lane & 15;
  const int lofs = lane * 8;

  // ---- edge ids + gather bases (eidx loads issue first)
  const int be = blockIdx.x * 256 + wv * 32;
  const int e0 = be + ar, e1 = be + 16 + ar;
  const int ec0 = (e0 < NE) ? e0 : (NE - 1);
  const int ec1 = (e1 < NE) ? e1 : (NE - 1);
  const unsigned short* pUs0 = Ua + (size_t)eidx[ec0] * CH;
  const unsigned short* pUd0 = Ua + (size_t)eidx[NE + ec0] * CH;
  const unsigned short* pUs1 = Ua + (size_t)eidx[ec1] * CH;
  const unsigned short* pUd1 = Ua + (size_t)eidx[NE + ec1] * CH;

  // ---- stage P1b into LDS (barrier deferred past phase B)
  {
    const u4* s1 = (const u4*)(wp + 32768);
    u4* l = (u4*)lw;
#pragma unroll
    for (int i = 0; i < 8; ++i) {
      int o = i * 512 + tid;
      l[o] = s1[o];
    }
  }

  // ---- h^T accumulators (lane: edge ar, couts 16mt+4kg+i), b2a+b2b folded in
  f4 hacc[2][8];
#pragma unroll
  for (int mt = 0; mt < 8; ++mt) {
    f4 u = *(const f4*)(b2a + mt * 16 + kg * 4);
    f4 v = *(const f4*)(b2b + mt * 16 + kg * 4);
    hacc[0][mt] = u + v;
    hacc[1][mt] = u + v;
  }

  // ---- phase B: layer-2a. Gathers + W2a frags from L2 (shared across groups)
  {
    const unsigned short* P2a = wp + 65536;
#pragma unroll 2
    for (int u = 0; u < 8; ++u) {
      const int ko = u * 32 + kg * 8;
      u4 a0v = *(const u4*)(pUs0 + ko), d0v = *(const u4*)(pUd0 + ko);
      u4 a1v = *(const u4*)(pUs1 + ko), d1v = *(const u4*)(pUd1 + ko);
      FragU tb0, tb1;
#pragma unroll
      for (int i = 0; i < 4; ++i) {
        float lo0 = asf(a0v[i] << 16) + asf(d0v[i] << 16);
        float hi0 = asf(a0v[i] & 0xFFFF0000u) + asf(d0v[i] & 0xFFFF0000u);
        tb0.w[i] = cvtpk(fmaxf(lo0, 0.f), fmaxf(hi0, 0.f));
        float lo1 = asf(a1v[i] << 16) + asf(d1v[i] << 16);
        float hi1 = asf(a1v[i] & 0xFFFF0000u) + asf(d1v[i] & 0xFFFF0000u);
        tb1.w[i] = cvtpk(fmaxf(lo1, 0.f), fmaxf(hi1, 0.f));
      }
#pragma unroll
      for (int mt = 0; mt < 8; ++mt) {
        bf8 a2 = *(const bf8*)(P2a + (mt * 8 + u) * 512 + lofs);
        hacc[0][mt] = __builtin_amdgcn_mfma_f32_16x16x32_bf16(a2, tb0.h, hacc[0][mt], 0, 0, 0);
        hacc[1][mt] = __builtin_amdgcn_mfma_f32_16x16x32_bf16(a2, tb1.h, hacc[1][mt], 0, 0, 0);
      }
    }
  }

  __syncthreads();   // P1b staged

  // ---- phase A: net-b, group-sequential; P1b from LDS, P2b from L2
  {
    const unsigned short* P2b = wp + 98304;
#pragma unroll
    for (int g = 0; g < 2; ++g) {
      const int ecg = g ? ec1 : ec0;
      const float* pe = ef + (size_t)ecg * CI;
      FragU xe[4];
#pragma unroll
      for (int t = 0; t < 4; ++t) {
        const int c0 = t * 32 + kg * 8;
        f4 v0 = *(const f4*)(pe + c0);
        f4 v1 = *(const f4*)(pe + c0 + 4);
        xe[t].w[0] = cvtpk(v0[0], v0[1]); xe[t].w[1] = cvtpk(v0[2], v0[3]);
        xe[t].w[2] = cvtpk(v1[0], v1[1]); xe[t].w[3] = cvtpk(v1[2], v1[3]);
      }
#pragma unroll 2
      for (int c = 0; c < 8; ++c) {
        f4 t0 = *(const f4*)(b1b + c * 32 + kg * 8);
        f4 t1 = *(const f4*)(b1b + c * 32 + kg * 8 + 4);
#pragma unroll
        for (int t = 0; t < 4; ++t) {
          bf8 a0 = *(const bf8*)(lw + c * 4096 + t * 512 + lofs);
          bf8 a1 = *(const bf8*)(lw + c * 4096 + 2048 + t * 512 + lofs);
          t0 = __builtin_amdgcn_mfma_f32_16x16x32_bf16(a0, xe[t].h, t0, 0, 0, 0);
          t1 = __builtin_amdgcn_mfma_f32_16x16x32_bf16(a1, xe[t].h, t1, 0, 0, 0);
        }
        FragU bf_;
        bf_.w[0] = cvtpk(fmaxf(t0[0], 0.f), fmaxf(t0[1], 0.f));
        bf_.w[1] = cvtpk(fmaxf(t0[2], 0.f), fmaxf(t0[3], 0.f));
        bf_.w[2] = cvtpk(fmaxf(t1[0], 0.f), fmaxf(t1[1], 0.f));
        bf_.w[3] = cvtpk(fmaxf(t1[2], 0.f), fmaxf(t1[3], 0.f));
#pragma unroll
        for (int mt = 0; mt < 8; ++mt) {
          bf8 a2 = *(const bf8*)(P2b + (mt * 8 + c) * 512 + lofs);
          hacc[g][mt] = __builtin_amdgcn_mfma_f32_16x16x32_bf16(a2, bf_.h, hacc[g][mt], 0, 0, 0);
        }
      }
    }
  }

  // ---- phase C: InstanceNorm + relu + residual + store, per group
#pragma unroll
  for (int g = 0; g < 2; ++g) {
    float sum = 0.f, sq = 0.f;
#pragma unroll
    for (int mt = 0; mt < 8; ++mt)
#pragma unroll
      for (int i = 0; i < 4; ++i) { float v = hacc[g][mt][i]; sum += v; sq += v * v; }
    sum += __shfl_xor(sum, 16); sum += __shfl_xor(sum, 32);
    sq  += __shfl_xor(sq, 16);  sq  += __shfl_xor(sq, 32);
    const float mu = sum * (1.0f / 128.0f);
    const float var = sq * (1.0f / 128.0f) - mu * mu;
    const float rs = rsqrtf(var + EPSI);
    const int e = g ? e1 : e0;
    if (e < NE) {
      float* po = out + (size_t)e * CI;
      const float* pr = ef + (size_t)e * CI;
#pragma unroll
      for (int mt = 0; mt < 8; ++mt) {
        f4 r = *(const f4*)(pr + mt * 16 + kg * 4);
        f4 o;
#pragma unroll
        for (int i = 0; i < 4; ++i) {
          float n = (hacc[g][mt][i] - mu) * rs;
          o[i] = r[i] + fmaxf(n, 0.f);
        }
        *(f4*)(po + mt * 16 + kg * 4) = o;
      }
    }
  }
}

extern "C" void kernel_launch(void* const* d_in, const int* in_sizes, int n_in,
                              void* d_out, int out_size, void* d_ws, size_t ws_size,
                              hipStream_t stream) {
  const float* node = (const float*)d_in[0];
  const float* ef   = (const float*)d_in[1];
  const int* eidx   = (const int*)d_in[2];
  const float* W1a = (const float*)d_in[3];
  const float* b1a = (const float*)d_in[4];
  const float* W2a = (const float*)d_in[5];
  const float* b2a = (const float*)d_in[6];
  const float* W1b = (const float*)d_in[7];
  const float* b1b = (const float*)d_in[8];
  const float* W2b = (const float*)d_in[9];
  const float* b2b = (const float*)d_in[10];
  unsigned short* wp = (unsigned short*)d_ws;            // 256 KB packed weights
  unsigned short* Ua = wp + 131072;                       // 25.6 MB bf16 Ua
  float* outp = (float*)d_out;

  pack_weights<<<512, 256, 0, stream>>>(W1a, W1b, W2a, W2b, wp);
  node_pre<<<(NN + 63) / 64, 256, 0, stream>>>(node, b1a, wp, Ua);
  edge_fused<<<(NE + 255) / 256, 512, 0, stream>>>(
      Ua, ef, eidx, b1b, b2a, b2b, wp, outp);
}

// Round 7
// 410.116 us; speedup vs baseline: 1.1821x; 1.0829x over previous
//
#include <hip/hip_runtime.h>
#include <stdint.h>
#include <stddef.h>

#define NE 600000
#define NN 50000
#define CI 128
#define CH 256
#define EPSI 1e-5f

typedef __attribute__((ext_vector_type(8))) short bf8;
typedef __attribute__((ext_vector_type(4))) float f4;
typedef __attribute__((ext_vector_type(4))) unsigned int u4;

union FragU { bf8 h; uint32_t w[4]; };

__device__ __forceinline__ unsigned short f2bf(float f) {
  union { float f; uint32_t u; } v; v.f = f;
  uint32_t u = v.u;
  u += 0x7FFFu + ((u >> 16) & 1u);   // RNE
  return (unsigned short)(u >> 16);
}

__device__ __forceinline__ uint32_t cvtpk(float lo, float hi) {
  uint32_t r;
  asm("v_cvt_pk_bf16_f32 %0, %1, %2" : "=v"(r) : "v"(lo), "v"(hi));
  return r;
}

__device__ __forceinline__ float asf(uint32_t x) {
  union { uint32_t u; float f; } v; v.u = x; return v.f;
}

// non-temporal (evict-first) helpers for pure streams: keep L2/L3 for Ua
__device__ __forceinline__ f4 ntl4(const float* p) {
  return __builtin_nontemporal_load((const f4*)p);
}
__device__ __forceinline__ void nts4(float* p, f4 v) {
  __builtin_nontemporal_store(v, (f4*)p);
}
__device__ __forceinline__ int ntli(const int* p) {
  return __builtin_nontemporal_load(p);
}

// Weight pack (verified rounds 3-6):
//  P1 (layer1, per net, 64KB): tau-permuted so D-regs of chunk c land as
//    lane kg's hids {32c+8kg+0..7}.
//  P2 (layer2, per net, 64KB): u16 P2[mt][c][l][j] = W2[32c+(l>>4)*8+j][16mt+(l&15)]
// ws u16 layout: [0)P1a [32768)P1b [65536)P2a [98304)P2b [131072) Ua bf16 [NN][256]
__global__ void pack_weights(const float* __restrict__ W1a, const float* __restrict__ W1b,
                             const float* __restrict__ W2a, const float* __restrict__ W2b,
                             unsigned short* __restrict__ ws) {
  int i = blockIdx.x * 256 + threadIdx.x;
  if (i >= 4 * 32768) return;
  int m = i >> 15;
  int r = i & 32767;
  int j = r & 7;
  int l = (r >> 3) & 63;
  int kg = l >> 4, q = l & 15;
  float val;
  if (m < 2) {
    int t = (r >> 9) & 3;
    int tau = (r >> 11) & 1;
    int c = (r >> 12) & 7;
    int cin = 32 * t + kg * 8 + j;
    int hid = 32 * c + 8 * (q >> 2) + 4 * tau + (q & 3);
    const float* W1 = (m == 0) ? W1a : W1b;
    val = W1[cin * CH + hid];
  } else {
    int c = (r >> 9) & 7;
    int mt = (r >> 12) & 7;
    int hid = 32 * c + kg * 8 + j;
    int cout = 16 * mt + q;
    const float* W2 = (m == 2) ? W2a : W2b;
    val = W2[hid * CI + cout];
  }
  ws[(size_t)m * 32768 + r] = f2bf(val);
}

// Ua[n][hid] = bf16( node[n] @ W1a + 0.5*b1a )  (no relu; summed per edge later)
__global__ __launch_bounds__(256)
void node_pre(const float* __restrict__ node, const float* __restrict__ b1a,
              const unsigned short* __restrict__ wp, unsigned short* __restrict__ Ua) {
  const int tid = threadIdx.x;
  const int lane = tid & 63;
  const int wv = tid >> 6;
  const int kg = lane >> 4, ar = lane & 15;
  const int n0 = blockIdx.x * 64 + wv * 16 + ar;
  const bool okn = (n0 < NN);
  const int n = okn ? n0 : (NN - 1);
  const float* pn = node + (size_t)n * CI;

  FragU xn[4];
#pragma unroll
  for (int t = 0; t < 4; ++t) {
    const int c0 = t * 32 + kg * 8;
    f4 v0 = ntl4(pn + c0);
    f4 v1 = ntl4(pn + c0 + 4);
    xn[t].w[0] = cvtpk(v0[0], v0[1]); xn[t].w[1] = cvtpk(v0[2], v0[3]);
    xn[t].w[2] = cvtpk(v1[0], v1[1]); xn[t].w[3] = cvtpk(v1[2], v1[3]);
  }
  const int lofs = lane * 8;
#pragma unroll 1
  for (int c = 0; c < 8; ++c) {
    f4 t0 = *(const f4*)(b1a + c * 32 + kg * 8) * 0.5f;
    f4 t1 = *(const f4*)(b1a + c * 32 + kg * 8 + 4) * 0.5f;
    const unsigned short* p1 = wp + c * 4096;
#pragma unroll
    for (int t = 0; t < 4; ++t) {
      bf8 a0 = *(const bf8*)(p1 + t * 512 + lofs);
      bf8 a1 = *(const bf8*)(p1 + 2048 + t * 512 + lofs);
      t0 = __builtin_amdgcn_mfma_f32_16x16x32_bf16(a0, xn[t].h, t0, 0, 0, 0);
      t1 = __builtin_amdgcn_mfma_f32_16x16x32_bf16(a1, xn[t].h, t1, 0, 0, 0);
    }
    u4 q;
    q[0] = cvtpk(t0[0], t0[1]); q[1] = cvtpk(t0[2], t0[3]);
    q[2] = cvtpk(t1[0], t1[1]); q[3] = cvtpk(t1[2], t1[3]);
    if (okn) *(u4*)(Ua + (size_t)n * CH + c * 32 + kg * 8) = q;
  }
}

// Fused edge kernel: 1024 threads = 16 waves, 32 edges/wave (2 groups of 16).
// LDS: [0,32768) u16 = P1b copy, [32768,65536) u16 = P2b copy (128 KB).
// Streams (ef, eidx, out) use nt hints so Ua stays L3-resident for gathers.
__global__ __launch_bounds__(1024, 4)
void edge_fused(const unsigned short* __restrict__ Ua,
                const float* __restrict__ ef,
                const int* __restrict__ eidx,
                const float* __restrict__ b1b,
                const float* __restrict__ b2a, const float* __restrict__ b2b,
                const unsigned short* __restrict__ wp,
                float* __restrict__ out) {
  __shared__ __align__(16) unsigned short lw[65536];
  const int tid = threadIdx.x;
  const int lane = tid & 63;
  const int wv = tid >> 6;
  const int kg = lane >> 4, ar = lane & 15;
  const int lofs = lane * 8;

  // ---- stage W1b+W2b into LDS (barrier deferred until after phase B)
  {
    const u4* s1 = (const u4*)(wp + 32768);
    const u4* s2 = (const u4*)(wp + 98304);
    u4* l = (u4*)lw;
#pragma unroll
    for (int i = 0; i < 4; ++i) {
      int o = i * 1024 + tid;
      l[o] = s1[o];
      l[4096 + o] = s2[o];
    }
  }

  const int be = blockIdx.x * 512 + wv * 32;
  const int e0 = be + ar, e1 = be + 16 + ar;
  const int ec0 = (e0 < NE) ? e0 : (NE - 1);
  const int ec1 = (e1 < NE) ? e1 : (NE - 1);

  // ---- h^T accumulators (lane: edge ar, couts 16mt+4kg+i), b2a+b2b folded in
  f4 hacc[2][8];
#pragma unroll
  for (int mt = 0; mt < 8; ++mt) {
    f4 u = *(const f4*)(b2a + mt * 16 + kg * 4);
    f4 v = *(const f4*)(b2b + mt * 16 + kg * 4);
    hacc[0][mt] = u + v;
    hacc[1][mt] = u + v;
  }

  // ---- phase B: layer-2a. T1 = relu(Ua[src]+Ua[dst]) streamed per K-chunk;
  //      W2a A-frags from L2, shared by both groups.
  {
    const unsigned short* pUs0 = Ua + (size_t)ntli(eidx + ec0) * CH;
    const unsigned short* pUd0 = Ua + (size_t)ntli(eidx + NE + ec0) * CH;
    const unsigned short* pUs1 = Ua + (size_t)ntli(eidx + ec1) * CH;
    const unsigned short* pUd1 = Ua + (size_t)ntli(eidx + NE + ec1) * CH;
    const unsigned short* P2a = wp + 65536;
#pragma unroll 1
    for (int u = 0; u < 8; ++u) {
      const int ko = u * 32 + kg * 8;
      u4 a0 = *(const u4*)(pUs0 + ko), d0 = *(const u4*)(pUd0 + ko);
      u4 a1 = *(const u4*)(pUs1 + ko), d1 = *(const u4*)(pUd1 + ko);
      FragU tb0, tb1;
#pragma unroll
      for (int i = 0; i < 4; ++i) {
        float lo0 = asf(a0[i] << 16) + asf(d0[i] << 16);
        float hi0 = asf(a0[i] & 0xFFFF0000u) + asf(d0[i] & 0xFFFF0000u);
        tb0.w[i] = cvtpk(fmaxf(lo0, 0.f), fmaxf(hi0, 0.f));
        float lo1 = asf(a1[i] << 16) + asf(d1[i] << 16);
        float hi1 = asf(a1[i] & 0xFFFF0000u) + asf(d1[i] & 0xFFFF0000u);
        tb1.w[i] = cvtpk(fmaxf(lo1, 0.f), fmaxf(hi1, 0.f));
      }
#pragma unroll
      for (int mt = 0; mt < 8; ++mt) {
        bf8 a = *(const bf8*)(P2a + (mt * 8 + u) * 512 + lofs);
        hacc[0][mt] = __builtin_amdgcn_mfma_f32_16x16x32_bf16(a, tb0.h, hacc[0][mt], 0, 0, 0);
        hacc[1][mt] = __builtin_amdgcn_mfma_f32_16x16x32_bf16(a, tb1.h, hacc[1][mt], 0, 0, 0);
      }
    }
  }

  __syncthreads();   // LDS weights ready

  // ---- phase A: net-b from LDS weights, group-sequential
#pragma unroll
  for (int g = 0; g < 2; ++g) {
    const int ecg = g ? ec1 : ec0;
    const float* pe = ef + (size_t)ecg * CI;
    FragU xe[4];
#pragma unroll
    for (int t = 0; t < 4; ++t) {
      const int c0 = t * 32 + kg * 8;
      f4 v0 = ntl4(pe + c0);
      f4 v1 = ntl4(pe + c0 + 4);
      xe[t].w[0] = cvtpk(v0[0], v0[1]); xe[t].w[1] = cvtpk(v0[2], v0[3]);
      xe[t].w[2] = cvtpk(v1[0], v1[1]); xe[t].w[3] = cvtpk(v1[2], v1[3]);
    }
#pragma unroll 1
    for (int c = 0; c < 8; ++c) {
      f4 t0 = *(const f4*)(b1b + c * 32 + kg * 8);
      f4 t1 = *(const f4*)(b1b + c * 32 + kg * 8 + 4);
#pragma unroll
      for (int t = 0; t < 4; ++t) {
        bf8 a0 = *(const bf8*)(lw + c * 4096 + t * 512 + lofs);
        bf8 a1 = *(const bf8*)(lw + c * 4096 + 2048 + t * 512 + lofs);
        t0 = __builtin_amdgcn_mfma_f32_16x16x32_bf16(a0, xe[t].h, t0, 0, 0, 0);
        t1 = __builtin_amdgcn_mfma_f32_16x16x32_bf16(a1, xe[t].h, t1, 0, 0, 0);
      }
      FragU bf_;
      bf_.w[0] = cvtpk(fmaxf(t0[0], 0.f), fmaxf(t0[1], 0.f));
      bf_.w[1] = cvtpk(fmaxf(t0[2], 0.f), fmaxf(t0[3], 0.f));
      bf_.w[2] = cvtpk(fmaxf(t1[0], 0.f), fmaxf(t1[1], 0.f));
      bf_.w[3] = cvtpk(fmaxf(t1[2], 0.f), fmaxf(t1[3], 0.f));
#pragma unroll
      for (int mt = 0; mt < 8; ++mt) {
        bf8 a2 = *(const bf8*)(lw + 32768 + (mt * 8 + c) * 512 + lofs);
        hacc[g][mt] = __builtin_amdgcn_mfma_f32_16x16x32_bf16(a2, bf_.h, hacc[g][mt], 0, 0, 0);
      }
    }
  }

  // ---- phase C: InstanceNorm + relu + residual + store, per group
#pragma unroll
  for (int g = 0; g < 2; ++g) {
    float sum = 0.f, sq = 0.f;
#pragma unroll
    for (int mt = 0; mt < 8; ++mt)
#pragma unroll
      for (int i = 0; i < 4; ++i) { float v = hacc[g][mt][i]; sum += v; sq += v * v; }
    sum += __shfl_xor(sum, 16); sum += __shfl_xor(sum, 32);
    sq  += __shfl_xor(sq, 16);  sq  += __shfl_xor(sq, 32);
    const float mu = sum * (1.0f / 128.0f);
    const float var = sq * (1.0f / 128.0f) - mu * mu;
    const float rs = rsqrtf(var + EPSI);
    const int e = g ? e1 : e0;
    if (e < NE) {
      float* po = out + (size_t)e * CI;
      const float* pr = ef + (size_t)e * CI;
#pragma unroll
      for (int mt = 0; mt < 8; ++mt) {
        f4 r = ntl4(pr + mt * 16 + kg * 4);
        f4 o;
#pragma unroll
        for (int i = 0; i < 4; ++i) {
          float n = (hacc[g][mt][i] - mu) * rs;
          o[i] = r[i] + fmaxf(n, 0.f);
        }
        nts4(po + mt * 16 + kg * 4, o);
      }
    }
  }
}

extern "C" void kernel_launch(void* const* d_in, const int* in_sizes, int n_in,
                              void* d_out, int out_size, void* d_ws, size_t ws_size,
                              hipStream_t stream) {
  const float* node = (const float*)d_in[0];
  const float* ef   = (const float*)d_in[1];
  const int* eidx   = (const int*)d_in[2];
  const float* W1a = (const float*)d_in[3];
  const float* b1a = (const float*)d_in[4];
  const float* W2a = (const float*)d_in[5];
  const float* b2a = (const float*)d_in[6];
  const float* W1b = (const float*)d_in[7];
  const float* b1b = (const float*)d_in[8];
  const float* W2b = (const float*)d_in[9];
  const float* b2b = (const float*)d_in[10];
  unsigned short* wp = (unsigned short*)d_ws;            // 256 KB packed weights
  unsigned short* Ua = wp + 131072;                       // 25.6 MB bf16 Ua
  float* outp = (float*)d_out;

  pack_weights<<<512, 256, 0, stream>>>(W1a, W1b, W2a, W2b, wp);
  node_pre<<<(NN + 63) / 64, 256, 0, stream>>>(node, b1a, wp, Ua);
  edge_fused<<<(NE + 511) / 512, 1024, 0, stream>>>(
      Ua, ef, eidx, b1b, b2a, b2b, wp, outp);
}